// Round 1
// baseline (2045.079 us; speedup 1.0000x reference)
//
#include <hip/hip_runtime.h>
#include <cstdint>

typedef __attribute__((ext_vector_type(8))) short short8;
typedef __attribute__((ext_vector_type(4))) float f32x4;

__device__ __forceinline__ ushort f2bf(float x){
    uint32_t u = __float_as_uint(x);
    u = (u + 0x7FFFu + ((u >> 16) & 1u)) >> 16;
    return (ushort)u;
}

// ---------------- kernel 1: fp32 -> bf16 weight conversion ----------------
__global__ void k_conv(const float* __restrict__ W1, const float* __restrict__ W2,
                       const float* __restrict__ Emb,
                       ushort* __restrict__ W1b, ushort* __restrict__ W2b,
                       ushort* __restrict__ Eb){
    int i = blockIdx.x * 256 + threadIdx.x;   // grid 256 -> 65536
    W1b[i] = f2bf(W1[i]);
    W2b[i] = f2bf(W2[i]);
    Eb[i]  = f2bf(Emb[i]);
}

// -------- kernel 2: proj[v][h] = sum_e embed[v,e]*W_in[h,e]  (fp32) -------
__global__ void k_proj(const float* __restrict__ emb, const float* __restrict__ Win,
                       float* __restrict__ proj){
    __shared__ __align__(16) float se[256];
    int v = blockIdx.x, h = threadIdx.x;
    se[h] = emb[v*256 + h];
    __syncthreads();
    const float* wr = Win + h*256;
    float a0=0.f,a1=0.f,a2=0.f,a3=0.f;
    #pragma unroll
    for (int e = 0; e < 256; e += 4){
        float4 w = *(const float4*)(wr + e);
        a0 = fmaf(w.x, se[e+0], a0);
        a1 = fmaf(w.y, se[e+1], a1);
        a2 = fmaf(w.z, se[e+2], a2);
        a3 = fmaf(w.w, se[e+3], a3);
    }
    proj[v*256 + h] = (a0+a1)+(a2+a3);
}

// ---------------- kernel 3: ESN recurrence, fp32, W in VGPRs --------------
// 128 blocks (one per batch row) x 1024 threads.
// thread t: r = t&255 (output row), chunk = t>>8, owns W[r][chunk*64 .. +63].
__global__ __launch_bounds__(1024) void k_recur(const int* __restrict__ idx,
        const float* __restrict__ W, const float* __restrict__ proj,
        ushort* __restrict__ hs){
    __shared__ __align__(16) float s_h[256];
    __shared__ __align__(16) float s_part[1024];
    __shared__ int s_idx[2048];
    const int tid   = threadIdx.x;
    const int b     = blockIdx.x;
    const int r     = tid & 255;
    const int chunk = tid >> 8;

    for (int i = tid; i < 2048; i += 1024) s_idx[i] = idx[b*2048 + i];
    if (tid < 256) s_h[tid] = 0.f;

    float4 w4[16];
    {
        const float* wr = W + r*256 + chunk*64;
        #pragma unroll
        for (int j = 0; j < 16; ++j) w4[j] = *(const float4*)(wr + j*4);
    }
    __syncthreads();

    ushort* hrow = hs + (size_t)b * 2048 * 256;
    for (int t = 0; t < 2048; ++t){
        float u = 0.f;
        {
            int token = s_idx[t];
            if (tid < 256) u = proj[token*256 + tid];   // prefetch, hides under matvec
        }
        const float4* h4 = ((const float4*)s_h) + chunk*16;
        float a0=0.f,a1=0.f,a2=0.f,a3=0.f;
        #pragma unroll
        for (int j = 0; j < 16; ++j){
            float4 hv = h4[j];       // broadcast read (all lanes same addr)
            float4 wv = w4[j];
            a0 = fmaf(wv.x, hv.x, a0);
            a1 = fmaf(wv.y, hv.y, a1);
            a2 = fmaf(wv.z, hv.z, a2);
            a3 = fmaf(wv.w, hv.w, a3);
        }
        s_part[tid] = (a0+a1)+(a2+a3);
        __syncthreads();
        if (tid < 256){
            float pre = s_part[tid] + s_part[tid+256] + s_part[tid+512] + s_part[tid+768] + u;
            pre = fminf(20.f, fmaxf(-20.f, pre));
            float e  = __expf(2.f*pre);
            float th = __fdividef(e - 1.f, e + 1.f);
            float hn = 0.7f*s_h[tid] + 0.3f*th;
            s_h[tid] = hn;
            hrow[(size_t)t*256 + tid] = f2bf(hn);
        }
        __syncthreads();
    }
}

// ---------------- kernel 4: fused readout MLP + LN + lm_head --------------
// per block: 128 rows of BT. 512 threads = 8 waves, wave owns 16 rows.
// GEMM1 (swapped, D[e,m]) -> gelu -> A1_lds[m][e]
// GEMM2 (swapped, D[e2,m]) -> LN over e2 -> y_lds[m][e2] (overwrites A1)
// GEMM3 (unswapped, D[m,v]) -> fp32 out
__global__ __launch_bounds__(512) void k_readout(
        const ushort* __restrict__ hs,
        const ushort* __restrict__ W1b, const ushort* __restrict__ W2b,
        const ushort* __restrict__ Eb,
        const float* __restrict__ b1, const float* __restrict__ b2,
        const float* __restrict__ gamma, const float* __restrict__ beta,
        float* __restrict__ out){
    __shared__ __align__(16) char w_lds[65536];   // staged weight half: 128 rows x 256 bf16
    __shared__ __align__(16) char a_lds[65536];   // A1 / y tile: 128 rows x 256 bf16

    const int tid  = threadIdx.x;
    const int wid  = tid >> 6;
    const int lane = tid & 63;
    const int lr   = lane & 15;
    const int lg   = lane >> 4;
    const size_t m0 = (size_t)blockIdx.x * 128;
    const int ml   = wid*16 + lr;                 // this lane's m-row (local)

    // stage a 128x256 bf16 weight half into w_lds, XOR-swizzled
    auto stage = [&](const ushort* src){
        #pragma unroll
        for (int i = 0; i < 8; ++i){
            int off = (i*512 + tid) * 16;
            uint4 v = *(const uint4*)((const char*)src + off);
            int row = off >> 9;
            *(uint4*)(w_lds + (off ^ ((row & 7) << 4))) = v;
        }
    };
    // A-fragment of staged weight, tile n, k-chunk k0
    auto wfrag = [&](int n, int k0) -> short8 {
        int row  = n*16 + lr;
        int addr = (row << 9) + k0*64 + lg*16;
        addr ^= (row & 7) << 4;
        return __builtin_bit_cast(short8, *(const uint4*)(w_lds + addr));
    };
    // fragment of a_lds at own m-row, k-chunk k0
    auto afrag = [&](int k0) -> short8 {
        int addr = (ml << 9) + k0*64 + lg*16;
        addr ^= (ml & 7) << 4;
        return __builtin_bit_cast(short8, *(const uint4*)(a_lds + addr));
    };
    // write 4 consecutive e-values (8B) into a_lds[ml][ecol..ecol+3]
    auto awrite = [&](int ecol, f32x4 v){
        ushort4 pk;
        pk.x = f2bf(v[0]); pk.y = f2bf(v[1]); pk.z = f2bf(v[2]); pk.w = f2bf(v[3]);
        int addr = (ml << 9) + ecol*2;
        addr ^= (ml & 7) << 4;
        *(ushort4*)(a_lds + addr) = pk;
    };

    // ---- hs fragments straight from global (16B/lane, reused both halves) ----
    short8 hb[8];
    {
        const char* p = (const char*)(hs + (m0 + ml)*256) + lg*16;
        #pragma unroll
        for (int k0 = 0; k0 < 8; ++k0)
            hb[k0] = __builtin_bit_cast(short8, *(const uint4*)(p + k0*64));
    }

    // ================= GEMM1: A1 = gelu(hs @ W1.T + b1) =================
    #pragma unroll
    for (int h = 0; h < 2; ++h){
        __syncthreads();
        stage(W1b + h*128*256);
        __syncthreads();
        #pragma unroll
        for (int n = 0; n < 8; ++n){
            int eb = h*128 + n*16;
            float4 bi = *(const float4*)(b1 + eb + lg*4);
            f32x4 acc = {bi.x, bi.y, bi.z, bi.w};
            #pragma unroll
            for (int k0 = 0; k0 < 8; ++k0)
                acc = __builtin_amdgcn_mfma_f32_16x16x32_bf16(wfrag(n,k0), hb[k0], acc, 0,0,0);
            f32x4 g;
            #pragma unroll
            for (int q = 0; q < 4; ++q){
                float x = acc[q];
                g[q] = 0.5f*x*(1.f + erff(x*0.70710678118654752440f));
            }
            awrite(eb + lg*4, g);
        }
    }

    // ================= GEMM2: o = A1 @ W2.T + b2 =================
    short8 ab[8];
    __syncthreads();
    #pragma unroll
    for (int k0 = 0; k0 < 8; ++k0) ab[k0] = afrag(k0);
    f32x4 oacc[16];
    #pragma unroll
    for (int h = 0; h < 2; ++h){
        __syncthreads();
        stage(W2b + h*128*256);
        __syncthreads();
        #pragma unroll
        for (int n = 0; n < 8; ++n){
            int eb = h*128 + n*16;
            float4 bi = *(const float4*)(b2 + eb + lg*4);
            f32x4 acc = {bi.x, bi.y, bi.z, bi.w};
            #pragma unroll
            for (int k0 = 0; k0 < 8; ++k0)
                acc = __builtin_amdgcn_mfma_f32_16x16x32_bf16(wfrag(n,k0), ab[k0], acc, 0,0,0);
            oacc[h*8+n] = acc;
        }
    }

    // ================= LayerNorm over e2 (row dim of swapped D2) =================
    {
        float sum = 0.f, ss = 0.f;
        #pragma unroll
        for (int i = 0; i < 16; ++i){
            #pragma unroll
            for (int q = 0; q < 4; ++q){ float x = oacc[i][q]; sum += x; ss += x*x; }
        }
        sum += __shfl_xor(sum, 16); ss += __shfl_xor(ss, 16);
        sum += __shfl_xor(sum, 32); ss += __shfl_xor(ss, 32);
        float mu   = sum * (1.f/256.f);
        float var  = ss * (1.f/256.f) - mu*mu;
        float rstd = rsqrtf(var + 1e-5f);
        #pragma unroll
        for (int i = 0; i < 16; ++i){
            int ecol = (i >> 3)*128 + (i & 7)*16 + lg*4;
            float4 g4 = *(const float4*)(gamma + ecol);
            float4 t4 = *(const float4*)(beta + ecol);
            f32x4 y;
            y[0] = (oacc[i][0]-mu)*rstd*g4.x + t4.x;
            y[1] = (oacc[i][1]-mu)*rstd*g4.y + t4.y;
            y[2] = (oacc[i][2]-mu)*rstd*g4.z + t4.z;
            y[3] = (oacc[i][3]-mu)*rstd*g4.w + t4.w;
            awrite(ecol, y);
        }
    }

    // ================= GEMM3: logits = y @ embed.T (unswapped) =================
    __syncthreads();
    #pragma unroll
    for (int k0 = 0; k0 < 8; ++k0) ab[k0] = afrag(k0);   // y fragments
    #pragma unroll
    for (int h = 0; h < 2; ++h){
        __syncthreads();
        stage(Eb + h*128*256);
        __syncthreads();
        #pragma unroll
        for (int n = 0; n < 8; ++n){
            f32x4 acc = {0.f,0.f,0.f,0.f};
            #pragma unroll
            for (int k0 = 0; k0 < 8; ++k0)
                acc = __builtin_amdgcn_mfma_f32_16x16x32_bf16(ab[k0], wfrag(n,k0), acc, 0,0,0);
            int v = h*128 + n*16 + lr;
            float* op = out + (m0 + wid*16 + lg*4)*256 + v;
            op[0]   = acc[0];
            op[256] = acc[1];
            op[512] = acc[2];
            op[768] = acc[3];
        }
    }
}

// --------------------------------------------------------------------------
extern "C" void kernel_launch(void* const* d_in, const int* in_sizes, int n_in,
                              void* d_out, int out_size, void* d_ws, size_t ws_size,
                              hipStream_t stream){
    const int*   idx   = (const int*)d_in[0];
    const float* embed = (const float*)d_in[1];
    const float* W_in  = (const float*)d_in[2];
    const float* W     = (const float*)d_in[3];
    const float* W1    = (const float*)d_in[4];
    const float* b1    = (const float*)d_in[5];
    const float* W2    = (const float*)d_in[6];
    const float* b2    = (const float*)d_in[7];
    const float* gamma = (const float*)d_in[8];
    const float* beta  = (const float*)d_in[9];

    char* ws = (char*)d_ws;
    float*  proj = (float*)ws;                    // 256 KB fp32
    ushort* W1b  = (ushort*)(ws + 262144);        // 128 KB bf16
    ushort* W2b  = (ushort*)(ws + 393216);        // 128 KB
    ushort* Eb   = (ushort*)(ws + 524288);        // 128 KB
    ushort* hs   = (ushort*)(ws + 1048576);       // 134.2 MB bf16 [B*T, 256]
    if (ws_size < (size_t)135266304) return;      // ws too small -> recognizable absmax fail

    k_conv   <<<256, 256, 0, stream>>>(W1, W2, embed, W1b, W2b, Eb);
    k_proj   <<<256, 256, 0, stream>>>(embed, W_in, proj);
    k_recur  <<<128, 1024, 0, stream>>>(idx, W, proj, hs);
    k_readout<<<2048, 512, 0, stream>>>(hs, W1b, W2b, Eb, b1, b2, gamma, beta, (float*)d_out);
}

// Round 2
// 1993.022 us; speedup vs baseline: 1.0261x; 1.0261x over previous
//
#include <hip/hip_runtime.h>
#include <cstdint>

typedef __attribute__((ext_vector_type(8))) short short8;
typedef __attribute__((ext_vector_type(4))) float f32x4;

__device__ __forceinline__ ushort f2bf(float x){
    uint32_t u = __float_as_uint(x);
    u = (u + 0x7FFFu + ((u >> 16) & 1u)) >> 16;
    return (ushort)u;
}

// ---------------- kernel 1: fp32 -> bf16 weight conversion ----------------
__global__ void k_conv(const float* __restrict__ W1, const float* __restrict__ W2,
                       const float* __restrict__ Emb,
                       ushort* __restrict__ W1b, ushort* __restrict__ W2b,
                       ushort* __restrict__ Eb){
    int i = blockIdx.x * 256 + threadIdx.x;   // grid 256 -> 65536
    W1b[i] = f2bf(W1[i]);
    W2b[i] = f2bf(W2[i]);
    Eb[i]  = f2bf(Emb[i]);
}

// -------- kernel 2: proj[v][h] = sum_e embed[v,e]*W_in[h,e]  (fp32) -------
__global__ void k_proj(const float* __restrict__ emb, const float* __restrict__ Win,
                       float* __restrict__ proj){
    __shared__ __align__(16) float se[256];
    int v = blockIdx.x, h = threadIdx.x;
    se[h] = emb[v*256 + h];
    __syncthreads();
    const float* wr = Win + h*256;
    float a0=0.f,a1=0.f,a2=0.f,a3=0.f;
    #pragma unroll
    for (int e = 0; e < 256; e += 4){
        float4 w = *(const float4*)(wr + e);
        a0 = fmaf(w.x, se[e+0], a0);
        a1 = fmaf(w.y, se[e+1], a1);
        a2 = fmaf(w.z, se[e+2], a2);
        a3 = fmaf(w.w, se[e+3], a3);
    }
    proj[v*256 + h] = (a0+a1)+(a2+a3);
}

// ---------------- kernel 3: ESN recurrence, fp32, W in VGPRs --------------
// 128 blocks (one per batch row) x 512 threads (8 waves, 2/SIMD).
// thread t: c = t&7 (k-octant), rg = t>>3 (0..63); owns rows {rg+64q} x cols [32c,32c+32).
// In-wave octet reduction via shfl_xor(1,2,4); lanes c<4 finalize row rg+64c.
// W chunks loaded pre-rotated by c so LDS reads are bank-conflict-free and all
// register arrays are compile-time indexed.
__global__ __launch_bounds__(512) void k_recur(const int* __restrict__ idx,
        const float* __restrict__ W, const float* __restrict__ proj,
        ushort* __restrict__ hs){
    __shared__ __align__(16) float s_h[2][256];
    __shared__ int s_idx[2048];
    const int tid = threadIdx.x;
    const int b   = blockIdx.x;
    const int c   = tid & 7;
    const int rg  = tid >> 3;

    for (int i = tid; i < 2048; i += 512) s_idx[i] = idx[b*2048 + i];
    if (tid < 256) s_h[0][tid] = 0.f;

    // W[rg+64q][32c .. 32c+31], chunk j holds rotated chunk (j+c)&7
    float4 w4[4][8];
    #pragma unroll
    for (int q = 0; q < 4; ++q){
        const float* wr = W + (rg + 64*q)*256 + c*32;
        #pragma unroll
        for (int j = 0; j < 8; ++j)
            w4[q][j] = *(const float4*)(wr + 4*((j + c) & 7));
    }
    __syncthreads();

    const int myrow = rg + 64*c;              // valid when c<4
    float h_prev = 0.f;
    ushort* hrow = hs + (size_t)b * 2048 * 256;
    int cur = 0;
    for (int t = 0; t < 2048; ++t){
        int token = s_idx[t];
        float u = 0.f;
        if (c < 4) u = proj[token*256 + myrow];    // issued early, consumed late

        const float4* h4 = (const float4*)(&s_h[cur][c*32]);
        f32x4 a0 = {0.f,0.f,0.f,0.f}, a1 = a0, a2 = a0, a3 = a0;
        #pragma unroll
        for (int j = 0; j < 8; ++j){
            float4 hv = h4[(j + c) & 7];           // LDS addr runtime, regs static
            float4 w0 = w4[0][j], w1 = w4[1][j], w2 = w4[2][j], w3 = w4[3][j];
            a0[0]=fmaf(w0.x,hv.x,a0[0]); a0[1]=fmaf(w0.y,hv.y,a0[1]);
            a0[2]=fmaf(w0.z,hv.z,a0[2]); a0[3]=fmaf(w0.w,hv.w,a0[3]);
            a1[0]=fmaf(w1.x,hv.x,a1[0]); a1[1]=fmaf(w1.y,hv.y,a1[1]);
            a1[2]=fmaf(w1.z,hv.z,a1[2]); a1[3]=fmaf(w1.w,hv.w,a1[3]);
            a2[0]=fmaf(w2.x,hv.x,a2[0]); a2[1]=fmaf(w2.y,hv.y,a2[1]);
            a2[2]=fmaf(w2.z,hv.z,a2[2]); a2[3]=fmaf(w2.w,hv.w,a2[3]);
            a3[0]=fmaf(w3.x,hv.x,a3[0]); a3[1]=fmaf(w3.y,hv.y,a3[1]);
            a3[2]=fmaf(w3.z,hv.z,a3[2]); a3[3]=fmaf(w3.w,hv.w,a3[3]);
        }
        float s0 = (a0[0]+a0[1])+(a0[2]+a0[3]);
        float s1 = (a1[0]+a1[1])+(a1[2]+a1[3]);
        float s2 = (a2[0]+a2[1])+(a2[2]+a2[3]);
        float s3 = (a3[0]+a3[1])+(a3[2]+a3[3]);
        s0 += __shfl_xor(s0,1); s0 += __shfl_xor(s0,2); s0 += __shfl_xor(s0,4);
        s1 += __shfl_xor(s1,1); s1 += __shfl_xor(s1,2); s1 += __shfl_xor(s1,4);
        s2 += __shfl_xor(s2,1); s2 += __shfl_xor(s2,2); s2 += __shfl_xor(s2,4);
        s3 += __shfl_xor(s3,1); s3 += __shfl_xor(s3,2); s3 += __shfl_xor(s3,4);
        if (c < 4){
            float pre = (c==0 ? s0 : c==1 ? s1 : c==2 ? s2 : s3) + u;
            pre = fminf(20.f, fmaxf(-20.f, pre));
            float e  = __expf(2.f*pre);
            float th = 1.f - __fdividef(2.f, e + 1.f);
            float hn = 0.7f*h_prev + 0.3f*th;
            h_prev = hn;
            s_h[cur^1][myrow] = hn;
            hrow[(size_t)t*256 + myrow] = f2bf(hn);
        }
        __syncthreads();
        cur ^= 1;
    }
}

// ---------------- kernel 4: fused readout MLP + LN + lm_head --------------
// per block: 128 rows of BT. 512 threads = 8 waves, wave owns 16 rows.
// GEMM1 (swapped, D[e,m]) -> gelu -> A1_lds[m][e]
// GEMM2 (swapped, D[e2,m]) -> LN over e2 -> y_lds[m][e2] (overwrites A1)
// GEMM3 (unswapped, D[m,v]) -> fp32 out
__global__ __launch_bounds__(512) void k_readout(
        const ushort* __restrict__ hs,
        const ushort* __restrict__ W1b, const ushort* __restrict__ W2b,
        const ushort* __restrict__ Eb,
        const float* __restrict__ b1, const float* __restrict__ b2,
        const float* __restrict__ gamma, const float* __restrict__ beta,
        float* __restrict__ out){
    __shared__ __align__(16) char w_lds[65536];   // staged weight half: 128 rows x 256 bf16
    __shared__ __align__(16) char a_lds[65536];   // A1 / y tile: 128 rows x 256 bf16

    const int tid  = threadIdx.x;
    const int wid  = tid >> 6;
    const int lane = tid & 63;
    const int lr   = lane & 15;
    const int lg   = lane >> 4;
    const size_t m0 = (size_t)blockIdx.x * 128;
    const int ml   = wid*16 + lr;                 // this lane's m-row (local)

    // stage a 128x256 bf16 weight half into w_lds, XOR-swizzled
    auto stage = [&](const ushort* src){
        #pragma unroll
        for (int i = 0; i < 8; ++i){
            int off = (i*512 + tid) * 16;
            uint4 v = *(const uint4*)((const char*)src + off);
            int row = off >> 9;
            *(uint4*)(w_lds + (off ^ ((row & 7) << 4))) = v;
        }
    };
    // A-fragment of staged weight, tile n, k-chunk k0
    auto wfrag = [&](int n, int k0) -> short8 {
        int row  = n*16 + lr;
        int addr = (row << 9) + k0*64 + lg*16;
        addr ^= (row & 7) << 4;
        return __builtin_bit_cast(short8, *(const uint4*)(w_lds + addr));
    };
    // fragment of a_lds at own m-row, k-chunk k0
    auto afrag = [&](int k0) -> short8 {
        int addr = (ml << 9) + k0*64 + lg*16;
        addr ^= (ml & 7) << 4;
        return __builtin_bit_cast(short8, *(const uint4*)(a_lds + addr));
    };
    // write 4 consecutive e-values (8B) into a_lds[ml][ecol..ecol+3]
    auto awrite = [&](int ecol, f32x4 v){
        ushort4 pk;
        pk.x = f2bf(v[0]); pk.y = f2bf(v[1]); pk.z = f2bf(v[2]); pk.w = f2bf(v[3]);
        int addr = (ml << 9) + ecol*2;
        addr ^= (ml & 7) << 4;
        *(ushort4*)(a_lds + addr) = pk;
    };

    // ---- hs fragments straight from global (16B/lane, reused both halves) ----
    short8 hb[8];
    {
        const char* p = (const char*)(hs + (m0 + ml)*256) + lg*16;
        #pragma unroll
        for (int k0 = 0; k0 < 8; ++k0)
            hb[k0] = __builtin_bit_cast(short8, *(const uint4*)(p + k0*64));
    }

    // ================= GEMM1: A1 = gelu(hs @ W1.T + b1) =================
    #pragma unroll
    for (int h = 0; h < 2; ++h){
        __syncthreads();
        stage(W1b + h*128*256);
        __syncthreads();
        #pragma unroll
        for (int n = 0; n < 8; ++n){
            int eb = h*128 + n*16;
            float4 bi = *(const float4*)(b1 + eb + lg*4);
            f32x4 acc = {bi.x, bi.y, bi.z, bi.w};
            #pragma unroll
            for (int k0 = 0; k0 < 8; ++k0)
                acc = __builtin_amdgcn_mfma_f32_16x16x32_bf16(wfrag(n,k0), hb[k0], acc, 0,0,0);
            f32x4 g;
            #pragma unroll
            for (int q = 0; q < 4; ++q){
                float x = acc[q];
                g[q] = 0.5f*x*(1.f + erff(x*0.70710678118654752440f));
            }
            awrite(eb + lg*4, g);
        }
    }

    // ================= GEMM2: o = A1 @ W2.T + b2 =================
    short8 ab[8];
    __syncthreads();
    #pragma unroll
    for (int k0 = 0; k0 < 8; ++k0) ab[k0] = afrag(k0);
    f32x4 oacc[16];
    #pragma unroll
    for (int h = 0; h < 2; ++h){
        __syncthreads();
        stage(W2b + h*128*256);
        __syncthreads();
        #pragma unroll
        for (int n = 0; n < 8; ++n){
            int eb = h*128 + n*16;
            float4 bi = *(const float4*)(b2 + eb + lg*4);
            f32x4 acc = {bi.x, bi.y, bi.z, bi.w};
            #pragma unroll
            for (int k0 = 0; k0 < 8; ++k0)
                acc = __builtin_amdgcn_mfma_f32_16x16x32_bf16(wfrag(n,k0), ab[k0], acc, 0,0,0);
            oacc[h*8+n] = acc;
        }
    }

    // ================= LayerNorm over e2 (row dim of swapped D2) =================
    {
        float sum = 0.f, ss = 0.f;
        #pragma unroll
        for (int i = 0; i < 16; ++i){
            #pragma unroll
            for (int q = 0; q < 4; ++q){ float x = oacc[i][q]; sum += x; ss += x*x; }
        }
        sum += __shfl_xor(sum, 16); ss += __shfl_xor(ss, 16);
        sum += __shfl_xor(sum, 32); ss += __shfl_xor(ss, 32);
        float mu   = sum * (1.f/256.f);
        float var  = ss * (1.f/256.f) - mu*mu;
        float rstd = rsqrtf(var + 1e-5f);
        #pragma unroll
        for (int i = 0; i < 16; ++i){
            int ecol = (i >> 3)*128 + (i & 7)*16 + lg*4;
            float4 g4 = *(const float4*)(gamma + ecol);
            float4 t4 = *(const float4*)(beta + ecol);
            f32x4 y;
            y[0] = (oacc[i][0]-mu)*rstd*g4.x + t4.x;
            y[1] = (oacc[i][1]-mu)*rstd*g4.y + t4.y;
            y[2] = (oacc[i][2]-mu)*rstd*g4.z + t4.z;
            y[3] = (oacc[i][3]-mu)*rstd*g4.w + t4.w;
            awrite(ecol, y);
        }
    }

    // ================= GEMM3: logits = y @ embed.T (unswapped) =================
    __syncthreads();
    #pragma unroll
    for (int k0 = 0; k0 < 8; ++k0) ab[k0] = afrag(k0);   // y fragments
    #pragma unroll
    for (int h = 0; h < 2; ++h){
        __syncthreads();
        stage(Eb + h*128*256);
        __syncthreads();
        #pragma unroll
        for (int n = 0; n < 8; ++n){
            f32x4 acc = {0.f,0.f,0.f,0.f};
            #pragma unroll
            for (int k0 = 0; k0 < 8; ++k0)
                acc = __builtin_amdgcn_mfma_f32_16x16x32_bf16(ab[k0], wfrag(n,k0), acc, 0,0,0);
            int v = h*128 + n*16 + lr;
            float* op = out + (m0 + wid*16 + lg*4)*256 + v;
            op[0]   = acc[0];
            op[256] = acc[1];
            op[512] = acc[2];
            op[768] = acc[3];
        }
    }
}

// --------------------------------------------------------------------------
extern "C" void kernel_launch(void* const* d_in, const int* in_sizes, int n_in,
                              void* d_out, int out_size, void* d_ws, size_t ws_size,
                              hipStream_t stream){
    const int*   idx   = (const int*)d_in[0];
    const float* embed = (const float*)d_in[1];
    const float* W_in  = (const float*)d_in[2];
    const float* W     = (const float*)d_in[3];
    const float* W1    = (const float*)d_in[4];
    const float* b1    = (const float*)d_in[5];
    const float* W2    = (const float*)d_in[6];
    const float* b2    = (const float*)d_in[7];
    const float* gamma = (const float*)d_in[8];
    const float* beta  = (const float*)d_in[9];

    char* ws = (char*)d_ws;
    float*  proj = (float*)ws;                    // 256 KB fp32
    ushort* W1b  = (ushort*)(ws + 262144);        // 128 KB bf16
    ushort* W2b  = (ushort*)(ws + 393216);        // 128 KB
    ushort* Eb   = (ushort*)(ws + 524288);        // 128 KB
    ushort* hs   = (ushort*)(ws + 1048576);       // 134.2 MB bf16 [B*T, 256]
    if (ws_size < (size_t)135266304) return;      // ws too small -> recognizable absmax fail

    k_conv   <<<256, 256, 0, stream>>>(W1, W2, embed, W1b, W2b, Eb);
    k_proj   <<<256, 256, 0, stream>>>(embed, W_in, proj);
    k_recur  <<<128, 512, 0, stream>>>(idx, W, proj, hs);
    k_readout<<<2048, 512, 0, stream>>>(hs, W1b, W2b, Eb, b1, b2, gamma, beta, (float*)d_out);
}